// Round 3
// baseline (187.349 us; speedup 1.0000x reference)
//
#include <hip/hip_runtime.h>
#include <hip/hip_bf16.h>
#include <math.h>

#define Bsz 2048
#define Lsz 1024
#define SW  8   // waves (batches) per scan block

// ws layout (float offsets)
#define OFF_G   0        // Gram               64x64
#define OFF_GC  4096     // c_v * G[v][:]      64x64
#define OFF_P   8192     // table @ (read_w@out_w)  64x64
#define OFF_GV  12288    // g per token        64
#define OFF_BC  12352    // read_b@out_w+out_b 64

// ---------------- fused prep: 64 blocks x 512 threads; every block builds the
// full 64-token table in LDS (redundant, tiny), block b writes Gram/Gc/P row b.
__global__ __launch_bounds__(512) void prep_kernel(
    const float* __restrict__ embed_W, const float* __restrict__ ff_w1, const float* __restrict__ ff_b1,
    const float* __restrict__ ff_w2, const float* __restrict__ ff_b2, const float* __restrict__ ln_g,
    const float* __restrict__ ln_b, const float* __restrict__ gate_w1, const float* __restrict__ gate_b1,
    const float* __restrict__ gate_w2, const float* __restrict__ gate_b2, const float* __restrict__ read_w,
    const float* __restrict__ read_b, const float* __restrict__ out_w, const float* __restrict__ out_b,
    float* __restrict__ ws)
{
    __shared__ float shE[4096];      // embeddings 64x64
    __shared__ float shZ[8192];      // relu(E@W1+b1) 64x128; later reused: Wc(4096) + U(1088)
    __shared__ float shH[4096];      // x, then normalized h
    __shared__ float shHT[65 * 64];  // h transposed, padded
    __shared__ float shc[64];        // denom, then c

    const int tid  = threadIdx.x;
    const int b    = blockIdx.x;
    const int wave = tid >> 6;
    const int lane = tid & 63;

    for (int i = tid; i < 4096; i += 512) shE[i] = embed_W[i];
    __syncthreads();

    // z = relu(E @ ff_w1 + b1): 64x128
    for (int idx = tid; idx < 8192; idx += 512) {
        const int v = idx >> 7, j = idx & 127;
        float a = ff_b1[j];
        const float* e = &shE[v << 6];
        #pragma unroll 8
        for (int i = 0; i < 64; ++i) a = fmaf(e[i], ff_w1[i * 128 + j], a);
        shZ[idx] = fmaxf(a, 0.0f);
    }
    __syncthreads();

    // x = E + z @ ff_w2 + b2
    for (int idx = tid; idx < 4096; idx += 512) {
        const int v = idx >> 6, i = idx & 63;
        float a = ff_b2[i];
        const float* z = &shZ[v << 7];
        #pragma unroll 8
        for (int j = 0; j < 128; ++j) a = fmaf(z[j], ff_w2[j * 64 + i], a);
        shH[idx] = a + shE[idx];
    }
    __syncthreads();

    // LayerNorm per token (wave-per-token, 8 tokens/wave) + denom
    for (int v = wave; v < 64; v += 8) {
        const float x = shH[(v << 6) + lane];
        float mu = x;
        #pragma unroll
        for (int off = 32; off > 0; off >>= 1) mu += __shfl_xor(mu, off);
        mu *= (1.0f / 64.0f);
        const float dd = x - mu;
        float var = dd * dd;
        #pragma unroll
        for (int off = 32; off > 0; off >>= 1) var += __shfl_xor(var, off);
        var *= (1.0f / 64.0f);
        const float rstd = rsqrtf(var + 1e-5f);
        const float hv = fmaf(dd * rstd, ln_g[lane], ln_b[lane]);
        shH[(v << 6) + lane] = hv;
        shHT[lane * 65 + v]  = hv;
        float dn = hv * hv;
        #pragma unroll
        for (int off = 32; off > 0; off >>= 1) dn += __shfl_xor(dn, off);
        if (lane == 0) shc[v] = dn + 1e-6f;   // denom for now
    }
    __syncthreads();

    float* shWc = shZ;          // 4096 floats (z no longer needed)
    float* shU  = shZ + 4096;   // 64*17 floats
    // gate hidden partials: 1024 (v,m) pairs
    for (int p = tid; p < 1024; p += 512) {
        const int v = p >> 4, m = p & 15;
        float um = gate_b1[m];
        const float* hv = &shH[v << 6];
        #pragma unroll 8
        for (int i = 0; i < 64; ++i) um = fmaf(hv[i], gate_w1[i * 16 + m], um);
        shU[v * 17 + m] = fmaxf(um, 0.0f) * gate_w2[m];
    }
    // Wc = read_w @ out_w
    for (int idx = tid; idx < 4096; idx += 512) {
        const int j = idx >> 6, i = idx & 63;
        float a = 0.0f;
        #pragma unroll 8
        for (int m = 0; m < 64; ++m) a = fmaf(read_w[(j << 6) + m], out_w[(m << 6) + i], a);
        shWc[idx] = a;
    }
    __syncthreads();

    // finalize g, c
    if (tid < 64) {
        const int v = tid;
        float a2 = gate_b2[0];
        #pragma unroll
        for (int m = 0; m < 16; ++m) a2 += shU[v * 17 + m];
        const float g = 1.0f / (1.0f + expf(-a2));
        const float c = g / shc[v];
        if (b == 0) ws[OFF_GV + v] = g;
        shc[v] = c;
    }
    __syncthreads();

    if (tid < 64) {
        // Gram + Gc row b
        float a = 0.0f;
        const float* hb = &shH[b << 6];
        #pragma unroll 8
        for (int j = 0; j < 64; ++j) a = fmaf(hb[j], shHT[j * 65 + tid], a);
        ws[OFF_G  + (b << 6) + tid] = a;
        ws[OFF_GC + (b << 6) + tid] = shc[b] * a;
    } else if (tid < 128) {
        // P row b
        const int i = tid - 64;
        float a = 0.0f;
        const float* hb = &shH[b << 6];
        #pragma unroll 8
        for (int j = 0; j < 64; ++j) a = fmaf(hb[j], shWc[(j << 6) + i], a);
        ws[OFF_P + (b << 6) + i] = a;
    } else if (tid < 192 && b == 0) {
        const int i = tid - 128;
        float a = out_b[i];
        #pragma unroll 8
        for (int j = 0; j < 64; ++j) a = fmaf(read_b[j], out_w[(j << 6) + i], a);
        ws[OFF_BC + i] = a;
    }
}

// ---------------- scan: one wave per batch; padded toks (no clamps), A/B
// 16-step pipeline; u via exec-mask trick (2 VALU instead of 4).
__global__ __launch_bounds__(SW * 64) void scan_kernel(const int* __restrict__ seq,
                                                       const float* __restrict__ ws,
                                                       float* __restrict__ out)
{
    __shared__ float ldsGc[65 * 64];   // rows 0..63 real, row 64 zeros (dummy token)
    __shared__ float ldsP[4096];
    __shared__ int   toks[SW][1104];   // [0..63]=dummy pad, [64+t]=seq token t; 16 slack
    __shared__ float sbuf[SW][64];
    __shared__ float ldsg[64];
    __shared__ float ldsbc[64];

    const int tid  = threadIdx.x;
    const int wave = tid >> 6;
    const int lane = tid & 63;

    {
        const float4* srcGc = (const float4*)(ws + OFF_GC);
        const float4* srcP  = (const float4*)(ws + OFF_P);
        float4* dGc = (float4*)ldsGc;
        float4* dP  = (float4*)ldsP;
        for (int i = tid; i < 1024; i += SW * 64) { dGc[i] = srcGc[i]; dP[i] = srcP[i]; }
    }
    if (tid < 64) {
        ldsGc[4096 + tid] = 0.0f;
        ldsg[tid]  = ws[OFF_GV + tid];
        ldsbc[tid] = ws[OFF_BC + tid];
    }
    const int b = blockIdx.x * SW + wave;
    int* T = toks[wave];
    if (lane < 16) ((int4*)T)[lane] = make_int4(64, 64, 64, 64);   // front pad
    {
        int4* dst = (int4*)(T + 64);
        const int4* src = (const int4*)(seq + (size_t)b * Lsz);
        for (int i = lane; i < 256; i += 64) dst[i] = src[i];
    }
    __syncthreads();

    const int tokL = T[1087];   // query token
    T[1087] = 64;               // step 1023 -> dummy (Gc row 64 = 0, lane 64 never matches)
    float D = ws[OFF_G + (tokL << 6) + lane];   // D_v = e_v . q
    float u = 0.0f;
    const int vlane = lane;

    int   tkA[16], tkB[16];
    float gcA[16], gcB[16];

    int tokv = T[1072 + lane];
    #pragma unroll
    for (int k = 0; k < 16; ++k) {
        tkA[k] = __builtin_amdgcn_readlane(tokv, 15 - k);
        gcA[k] = ldsGc[(tkA[k] << 6) + lane];
    }
    int tokvB = T[1056 + lane];

    for (int t0 = 1023; t0 > 0; t0 -= 32) {
        #pragma unroll
        for (int k = 0; k < 16; ++k) {
            tkB[k] = __builtin_amdgcn_readlane(tokvB, 15 - k);
            gcB[k] = ldsGc[(tkB[k] << 6) + lane];
        }
        const int tokvA2 = T[t0 + 17 + lane];   // next A block tokens (pad-safe)
        #pragma unroll
        for (int k = 0; k < 16; ++k) {
            const int tok   = tkA[k];
            const int dbits = __builtin_amdgcn_readlane(__float_as_int(D), tok);
            const float d   = __int_as_float(dbits);
            asm volatile("v_cmpx_eq_u32 vcc, %2, %3\n\t"
                         "v_add_f32 %0, %1, %0\n\t"
                         "s_mov_b64 exec, -1"
                         : "+v"(u) : "s"(dbits), "s"(tok), "v"(vlane) : "vcc");
            D = fmaf(-d, gcA[k], D);
        }
        #pragma unroll
        for (int k = 0; k < 16; ++k) {
            tkA[k] = __builtin_amdgcn_readlane(tokvA2, 15 - k);
            gcA[k] = ldsGc[(tkA[k] << 6) + lane];
        }
        const int tokvB2 = T[t0 + 1 + lane];    // next B block tokens (pad-safe)
        #pragma unroll
        for (int k = 0; k < 16; ++k) {
            const int tok   = tkB[k];
            const int dbits = __builtin_amdgcn_readlane(__float_as_int(D), tok);
            const float d   = __int_as_float(dbits);
            asm volatile("v_cmpx_eq_u32 vcc, %2, %3\n\t"
                         "v_add_f32 %0, %1, %0\n\t"
                         "s_mov_b64 exec, -1"
                         : "+v"(u) : "s"(dbits), "s"(tok), "v"(vlane) : "vcc");
            D = fmaf(-d, gcB[k], D);
        }
        tokvB = tokvB2;
    }

    // epilogue: s = g*u ; logits = s @ P + bc
    sbuf[wave][lane] = ldsg[lane] * u;
    float acc = ldsbc[lane];
    #pragma unroll 8
    for (int v = 0; v < 64; ++v)
        acc = fmaf(sbuf[wave][v], ldsP[(v << 6) + lane], acc);
    out[(size_t)b * 64 + lane] = acc;
}

extern "C" void kernel_launch(void* const* d_in, const int* in_sizes, int n_in,
                              void* d_out, int out_size, void* d_ws, size_t ws_size,
                              hipStream_t stream) {
    const int*   seq     = (const int*)  d_in[0];
    const float* embed_W = (const float*)d_in[1];
    const float* ff_w1   = (const float*)d_in[2];
    const float* ff_b1   = (const float*)d_in[3];
    const float* ff_w2   = (const float*)d_in[4];
    const float* ff_b2   = (const float*)d_in[5];
    const float* ln_g    = (const float*)d_in[6];
    const float* ln_b    = (const float*)d_in[7];
    const float* gate_w1 = (const float*)d_in[8];
    const float* gate_b1 = (const float*)d_in[9];
    const float* gate_w2 = (const float*)d_in[10];
    const float* gate_b2 = (const float*)d_in[11];
    const float* read_w  = (const float*)d_in[12];
    const float* read_b  = (const float*)d_in[13];
    const float* out_w   = (const float*)d_in[14];
    const float* out_b   = (const float*)d_in[15];
    float* ws  = (float*)d_ws;
    float* out = (float*)d_out;

    hipLaunchKernelGGL(prep_kernel, dim3(64), dim3(512), 0, stream,
                       embed_W, ff_w1, ff_b1, ff_w2, ff_b2, ln_g, ln_b,
                       gate_w1, gate_b1, gate_w2, gate_b2, read_w, read_b,
                       out_w, out_b, ws);
    hipLaunchKernelGGL(scan_kernel, dim3(Bsz / SW), dim3(SW * 64), 0, stream,
                       seq, ws, out);
}